// Round 5
// baseline (1254.676 us; speedup 1.0000x reference)
//
#include <hip/hip_runtime.h>
#include <math.h>

// CALIBRATION ROUND (2nd resubmit — rounds 3/4 failed on container/broker
// infra, not the kernel). The score dur_us includes ~180+ us of harness
// resets (768 MiB 0xAA poison @ ~118 us + d_in restore); our kernel dispatch
// is <117 us and invisible in the top-5 profile. This round: real scan (bit
// exact, unchanged output) + 15 opaque re-read passes of the input, so the
// kernel dispatch surfaces in the profile with its true duration and HBM
// counters. Per-pass time = dispatch_dur/16 ~= the 1x-read streaming floor.

#define T_STEPS 256
#define NPIX (256 * 256 * 3)
#define NV (NPIX / 4)   // 49152 float4 columns
#define PF 8            // prefetch depth
#define DUMMY_PASSES 15

__device__ __forceinline__ void sif_step(float4& mem, float4& cnt, float4 v) {
    mem.x += v.x; mem.y += v.y; mem.z += v.z; mem.w += v.w;
    bool fx = mem.x > 1.0f, fy = mem.y > 1.0f, fz = mem.z > 1.0f, fw = mem.w > 1.0f;
    cnt.x += fx ? 1.0f : 0.0f; cnt.y += fy ? 1.0f : 0.0f;
    cnt.z += fz ? 1.0f : 0.0f; cnt.w += fw ? 1.0f : 0.0f;
    mem.x = fx ? 0.0f : mem.x; mem.y = fy ? 0.0f : mem.y;
    mem.z = fz ? 0.0f : mem.z; mem.w = fw ? 0.0f : mem.w;
}

__global__ __launch_bounds__(64) void sif_kernel(const float* __restrict__ x,
                                                 float* __restrict__ out) {
    const int gid = blockIdx.x * blockDim.x + threadIdx.x;  // 0..NV-1
    const float4* __restrict__ p = reinterpret_cast<const float4*>(x) + gid;

    float4 mem = make_float4(0.f, 0.f, 0.f, 0.f);
    float4 cnt = make_float4(0.f, 0.f, 0.f, 0.f);

    float4 a[PF], b[PF];

    // ---- real pass (identical to round-2 kernel; bit-exact output) ----
#pragma unroll
    for (int k = 0; k < PF; ++k) a[k] = p[k * NV];

    for (int tb = 0; tb < T_STEPS / PF; ++tb) {
        if (tb + 1 < T_STEPS / PF) {
            const int base = (tb + 1) * PF;
#pragma unroll
            for (int k = 0; k < PF; ++k) b[k] = p[(base + k) * NV];
        }
#pragma unroll
        for (int k = 0; k < PF; ++k) sif_step(mem, cnt, a[k]);
#pragma unroll
        for (int k = 0; k < PF; ++k) a[k] = b[k];
    }

    // ---- calibration passes: re-read input 15x; no effect on output ----
    // Fresh opaque zero per pass defeats CSE/LICM of the loads (rule #17);
    // no "memory" clobbers, so MLP (8 loads in flight) is preserved.
#pragma unroll 1
    for (int r = 0; r < DUMMY_PASSES; ++r) {
        int z;
        asm volatile("s_mov_b32 %0, 0" : "=s"(z));
        const float4* __restrict__ q = p + z;
#pragma unroll 8
        for (int t = 0; t < T_STEPS; ++t) {
            float4 v = q[t * NV];
            asm volatile("" :: "v"(v.x), "v"(v.y), "v"(v.z), "v"(v.w));
        }
    }

    const float g = 1.0f / 2.2f;
    float4 r;
    r.x = powf(cnt.x * (1.0f / 256.0f), g);
    r.y = powf(cnt.y * (1.0f / 256.0f), g);
    r.z = powf(cnt.z * (1.0f / 256.0f), g);
    r.w = powf(cnt.w * (1.0f / 256.0f), g);
    reinterpret_cast<float4*>(out)[gid] = r;
}

extern "C" void kernel_launch(void* const* d_in, const int* in_sizes, int n_in,
                              void* d_out, int out_size, void* d_ws, size_t ws_size,
                              hipStream_t stream) {
    const float* x = (const float*)d_in[0];
    float* out = (float*)d_out;

    const int threads = 64;
    const int blocks = NV / threads;  // 768 blocks = 3 waves/CU
    sif_kernel<<<blocks, threads, 0, stream>>>(x, out);
}

// Round 6
// 267.722 us; speedup vs baseline: 4.6865x; 4.6865x over previous
//
#include <hip/hip_runtime.h>
#include <math.h>

// SIF node: x [T=256, H=256, W=256, C=3] fp32 -> out [256,256,3] fp32.
// Per pixel: sequential IF scan over T (mem += x; if mem>1: count++, mem=0),
// then out = pow(count/256, 1/2.2).
//
// Round-5 calibration established: harness reset overhead ~190 us/iter;
// kernel itself ran at ~72 us = 2.8 TB/s, latency-limited (11.8 GB/s/CU with
// only 24 KB/CU of loads in flight; effective loaded latency ~2 us). Neither
// HBM (6.3 TB/s) nor L3 is saturated. In-flight bytes/CU = 3072*PF regardless
// of vector width, so the ONLY lever is pipeline depth.
//
// This version: rolling 32-deep register pipeline. Each unrolled step:
//   wait oldest slot -> grab value -> REISSUE that slot t+32 ahead -> compute.
// Steady state: 32 float4 loads (32 KB) in flight per wave, 96 KB/CU (4x).
// All buffer indices are compile-time constants (rule #20: no scratch).
// Consume order is still t=0..255 -> bit-exact vs the JAX scan.

#define T_STEPS 256
#define NPIX (256 * 256 * 3)
#define NV (NPIX / 4)   // 49152 float4 columns
#define PF 32           // rolling pipeline depth; 256 % 32 == 0

__device__ __forceinline__ void sif_step(float4& mem, float4& cnt, float4 v) {
    mem.x += v.x; mem.y += v.y; mem.z += v.z; mem.w += v.w;
    bool fx = mem.x > 1.0f, fy = mem.y > 1.0f, fz = mem.z > 1.0f, fw = mem.w > 1.0f;
    cnt.x += fx ? 1.0f : 0.0f; cnt.y += fy ? 1.0f : 0.0f;
    cnt.z += fz ? 1.0f : 0.0f; cnt.w += fw ? 1.0f : 0.0f;
    mem.x = fx ? 0.0f : mem.x; mem.y = fy ? 0.0f : mem.y;
    mem.z = fz ? 0.0f : mem.z; mem.w = fw ? 0.0f : mem.w;
}

__global__ __launch_bounds__(64) void sif_kernel(const float* __restrict__ x,
                                                 float* __restrict__ out) {
    const int gid = blockIdx.x * 64 + threadIdx.x;  // 0..NV-1
    const float4* __restrict__ p = reinterpret_cast<const float4*>(x) + gid;

    float4 mem = make_float4(0.f, 0.f, 0.f, 0.f);
    float4 cnt = make_float4(0.f, 0.f, 0.f, 0.f);

    float4 buf[PF];  // statically-indexed only -> lives in VGPRs (~128)

    // Prologue: fill the pipe with t = 0..31.
#pragma unroll
    for (int k = 0; k < PF; ++k) buf[k] = p[k * NV];

    // Main: 7 groups. Group g consumes t = g*32+k and reissues t = g*32+32+k,
    // keeping ~32 loads outstanding at all times (no drain-and-refill).
    for (int g = 0; g < T_STEPS / PF - 1; ++g) {
        const int base = g * PF + PF;
#pragma unroll
        for (int k = 0; k < PF; ++k) {
            float4 v = buf[k];              // waits only the oldest load
            buf[k] = p[(base + k) * NV];    // refill slot immediately
            sif_step(mem, cnt, v);          // VALU under the memory latency
        }
    }

    // Epilogue: consume t = 224..255.
#pragma unroll
    for (int k = 0; k < PF; ++k) sif_step(mem, cnt, buf[k]);

    const float g = 1.0f / 2.2f;
    float4 r;
    r.x = powf(cnt.x * (1.0f / 256.0f), g);
    r.y = powf(cnt.y * (1.0f / 256.0f), g);
    r.z = powf(cnt.z * (1.0f / 256.0f), g);
    r.w = powf(cnt.w * (1.0f / 256.0f), g);
    reinterpret_cast<float4*>(out)[gid] = r;
}

extern "C" void kernel_launch(void* const* d_in, const int* in_sizes, int n_in,
                              void* d_out, int out_size, void* d_ws, size_t ws_size,
                              hipStream_t stream) {
    const float* x = (const float*)d_in[0];
    float* out = (float*)d_out;

    const int threads = 64;           // 1 wave/block -> uniform 3 waves/CU
    const int blocks = NV / threads;  // 768
    sif_kernel<<<blocks, threads, 0, stream>>>(x, out);
}